// Round 1
// baseline (943.656 us; speedup 1.0000x reference)
//
#include <hip/hip_runtime.h>

// Fused GQA attention layer for MI355X (gfx950).
// B=2 S=2048 E=4096 HQ=32 HKV=8 D=128 WINDOW=1024 SOFT_CAP=50 Q_PRE_ATTN=128
//
// Pipeline (all bf16 MFMA 16x16x32):
//   1. cast x -> bf16; transpose-cast Wq|Wk|Wv -> WqkvT[6144][4096], Wo -> WoT[4096][4096]
//   2. GEMM1: qkv_raw[4096][6144] = xb @ WqkvT^T            (m97-style, global_load_lds w16)
//   3. postprocess: l2norm + RoPE + q-scale -> q/k planes, v natural + v^T planes
//   4. flash attention (S^T = K*Q^T trick, fixed-max softmax since softcap bounds logits)
//   5. GEMM2: out = attn @ WoT^T  (fp32 out)
//
// Workspace layout (total 167,772,160 B = 160 MiB, regions reused over time):
//   [0,        33.5M)  xb        -> later vtb
//   [33.5M,    83.9M)  WqkvT     -> later qb|kb|vb
//   [83.9M,   117.4M)  WoT       (persistent)
//   [117.4M,  167.8M)  qkv_raw   -> later attn

typedef unsigned short u16;
typedef unsigned int   u32;
typedef __bf16 bf16x8 __attribute__((ext_vector_type(8)));
typedef float  f32x4  __attribute__((ext_vector_type(4)));

typedef __attribute__((address_space(1))) void* gas_ptr;
typedef __attribute__((address_space(3))) void* las_ptr;

__device__ __forceinline__ void load_lds16(const void* g, void* l) {
  // async global->LDS, 16B/lane; LDS dest = wave-uniform base + lane*16
  __builtin_amdgcn_global_load_lds((gas_ptr)g, (las_ptr)l, 16, 0, 0);
}

__device__ __forceinline__ u16 f2bf(float f) {
  u32 u = __builtin_bit_cast(u32, f);
  u += 0x7fffu + ((u >> 16) & 1u);   // RNE
  return (u16)(u >> 16);
}
__device__ __forceinline__ float bf2f(u16 h) {
  u32 u = ((u32)h) << 16;
  return __builtin_bit_cast(float, u);
}

// ---------------------------------------------------------------- cast x
__global__ __launch_bounds__(256) void cast_f32_bf16(const float* __restrict__ src,
                                                     u16* __restrict__ dst) {
  size_t i = ((size_t)blockIdx.x * 256 + threadIdx.x) * 8;
  float4 a = *(const float4*)(src + i);
  float4 b = *(const float4*)(src + i + 4);
  uint4 o;
  o.x = (u32)f2bf(a.x) | ((u32)f2bf(a.y) << 16);
  o.y = (u32)f2bf(a.z) | ((u32)f2bf(a.w) << 16);
  o.z = (u32)f2bf(b.x) | ((u32)f2bf(b.y) << 16);
  o.w = (u32)f2bf(b.z) | ((u32)f2bf(b.w) << 16);
  *(uint4*)(dst + i) = o;
}

// ------------------------------------------------- transpose-cast fp32->bf16
// src [R][C] row-major -> dst [C][R] row-major. R,C multiples of 32.
__global__ __launch_bounds__(256) void transpose_cast_f32_bf16(
    const float* __restrict__ src, u16* __restrict__ dst, int R, int C) {
  __shared__ float tile[32][33];
  const int tx = threadIdx.x & 31, ty = threadIdx.x >> 5;  // ty 0..7
  const int r0 = blockIdx.y * 32, c0 = blockIdx.x * 32;
#pragma unroll
  for (int i = 0; i < 4; ++i)
    tile[ty + i * 8][tx] = src[(size_t)(r0 + ty + i * 8) * C + (c0 + tx)];
  __syncthreads();
#pragma unroll
  for (int i = 0; i < 4; ++i)
    dst[(size_t)(c0 + ty + i * 8) * R + (r0 + tx)] = f2bf(tile[tx][ty + i * 8]);
}

// ------------------------------------------------- bf16 transpose for v planes
// per plane: src [2048][128] -> dst [128][2048]; grid (64, 4, 16planes)
__global__ __launch_bounds__(256) void transpose_v(const u16* __restrict__ src,
                                                   u16* __restrict__ dst) {
  __shared__ u16 tile[32][34];
  const int plane = blockIdx.z;
  const u16* s = src + (size_t)plane * 2048 * 128;
  u16* d = dst + (size_t)plane * 2048 * 128;
  const int tx = threadIdx.x & 31, ty = threadIdx.x >> 5;
  const int r0 = blockIdx.x * 32, c0 = blockIdx.y * 32;
#pragma unroll
  for (int i = 0; i < 4; ++i)
    tile[ty + i * 8][tx] = s[(size_t)(r0 + ty + i * 8) * 128 + (c0 + tx)];
  __syncthreads();
#pragma unroll
  for (int i = 0; i < 4; ++i)
    d[(size_t)(c0 + ty + i * 8) * 2048 + (r0 + tx)] = tile[tx][ty + i * 8];
}

// ---------------------------------------------------------------- GEMM (m97-style)
// C[M][N] = A[M][K] @ Bt[N][K]^T ; A,Bt bf16 row-major; 128x128 tile, BK=32,
// 4 waves, each 64x64 (4x4 of 16x16x32 MFMA). global_load_lds width 16.
template <int OUT_BF16>
__global__ __launch_bounds__(256) void gemm_bt(const u16* __restrict__ A,
                                               const u16* __restrict__ Bt,
                                               void* __restrict__ Cout,
                                               int M, int N, int K) {
  __shared__ __align__(16) u16 As[128 * 32];
  __shared__ __align__(16) u16 Bs[128 * 32];
  const int t = threadIdx.x;
  const int lane = t & 63, w = t >> 6;
  const int c = lane & 15, quad = lane >> 4;
  const int m0 = blockIdx.y * 128, n0 = blockIdx.x * 128;
  const int wm = (w >> 1) * 64, wn = (w & 1) * 64;
  const int srow = lane >> 2, sch = (lane & 3) * 8;

  f32x4 acc[4][4];
#pragma unroll
  for (int i = 0; i < 4; ++i)
#pragma unroll
    for (int j = 0; j < 4; ++j)
#pragma unroll
      for (int r = 0; r < 4; ++r) acc[i][j][r] = 0.0f;

  const u16* Ab = A + (size_t)(m0 + w * 16 + srow) * K + sch;
  const u16* Bb = Bt + (size_t)(n0 + w * 16 + srow) * K + sch;
  const size_t row64 = (size_t)64 * K;
  u16* AsW = &As[(w * 16) * 32];
  u16* AsW2 = &As[(64 + w * 16) * 32];
  u16* BsW = &Bs[(w * 16) * 32];
  u16* BsW2 = &Bs[(64 + w * 16) * 32];

  for (int k0 = 0; k0 < K; k0 += 32) {
    __syncthreads();                       // previous tile's reads done
    load_lds16(Ab + k0, AsW);
    load_lds16(Ab + row64 + k0, AsW2);
    load_lds16(Bb + k0, BsW);
    load_lds16(Bb + row64 + k0, BsW2);
    __syncthreads();                       // vmcnt(0) drained before barrier
    bf16x8 af[4], bfr[4];
#pragma unroll
    for (int i = 0; i < 4; ++i)
      af[i] = *(const bf16x8*)&As[(wm + i * 16 + c) * 32 + quad * 8];
#pragma unroll
    for (int j = 0; j < 4; ++j)
      bfr[j] = *(const bf16x8*)&Bs[(wn + j * 16 + c) * 32 + quad * 8];
#pragma unroll
    for (int i = 0; i < 4; ++i)
#pragma unroll
      for (int j = 0; j < 4; ++j)
        acc[i][j] = __builtin_amdgcn_mfma_f32_16x16x32_bf16(af[i], bfr[j], acc[i][j], 0, 0, 0);
  }

#pragma unroll
  for (int i = 0; i < 4; ++i) {
#pragma unroll
    for (int j = 0; j < 4; ++j) {
      const int col = n0 + wn + j * 16 + c;
#pragma unroll
      for (int r = 0; r < 4; ++r) {
        const int row = m0 + wm + i * 16 + quad * 4 + r;  // C/D: row=quad*4+reg, col=lane&15
        if (OUT_BF16)
          ((u16*)Cout)[(size_t)row * N + col] = f2bf(acc[i][j][r]);
        else
          ((float*)Cout)[(size_t)row * N + col] = acc[i][j][r];
      }
    }
  }
}

// ---------------------------------------------------------------- qkv postprocess
// one wave per (row, head-vector). hh: 0..31 q, 32..39 k, 40..47 v.
// lane i holds d=i and d=i+64 (the RoPE pair). l2norm via wave shuffle reduce.
__global__ __launch_bounds__(256) void qkv_post(const u16* __restrict__ raw,
                                                u16* __restrict__ qb,
                                                u16* __restrict__ kb,
                                                u16* __restrict__ vb) {
  const int t = threadIdx.x, lane = t & 63, w = t >> 6;
  const int idx = blockIdx.x * 4 + w;
  const int row = idx / 48, hh = idx - row * 48;
  const int b = row >> 11, pos = row & 2047;
  const u16* base = raw + (size_t)row * 6144 + hh * 128;
  const u16 r1 = base[lane], r2 = base[lane + 64];

  if (hh >= 40) {  // v: pass-through (no norm/rope)
    u16* dst = vb + ((size_t)((b * 8 + (hh - 40)) * 2048 + pos)) * 128;
    dst[lane] = r1;
    dst[lane + 64] = r2;
    return;
  }
  float v1 = bf2f(r1), v2 = bf2f(r2);
  float ss = v1 * v1 + v2 * v2;
#pragma unroll
  for (int off = 32; off >= 1; off >>= 1) ss += __shfl_xor(ss, off);
  const float rn = rsqrtf(ss * (1.0f / 128.0f) + 1e-6f);
  const float n1 = v1 * rn, n2 = v2 * rn;
  const float fr = exp2f(-(float)lane * 0.20762050593046f);  // 10000^(-lane/64)
  const float ang = (float)pos * fr;
  float sn, cs;
  sincosf(ang, &sn, &cs);
  float o1 = n1 * cs - n2 * sn;
  float o2 = n2 * cs + n1 * sn;
  u16* dst;
  if (hh < 32) {
    const float as_ = logf(floorf((float)(pos + 1) * (1.0f / 8192.0f)) + 1.0f) * 0.1f + 1.0f;
    const float sc = 0.088388347648318447f * as_;  // 128^-0.5 * attn_scale
    o1 *= sc;
    o2 *= sc;
    dst = qb + ((size_t)((b * 32 + hh) * 2048 + pos)) * 128;
  } else {
    dst = kb + ((size_t)((b * 8 + (hh - 32)) * 2048 + pos)) * 128;
  }
  dst[lane] = f2bf(o1);
  dst[lane + 64] = f2bf(o2);
}

// ---------------------------------------------------------------- flash attention
// Block: one (b, hq, 64-query tile); 4 waves. KV tiles of 64 keys.
// S^T = K*Q^T so C-layout rows are KEYS -> packed ds_write_b64 into key-contiguous
// P[q][key] (stride 72 shorts). Softcap bounds logits to +-50 -> fixed-max softmax.
// Q/K/VT LDS tiles use XOR chunk swizzle (applied on global addr so
// global_load_lds lane-contiguity is preserved) -> frag reads 2-way (free).
__global__ __launch_bounds__(256) void attn_fwd(const u16* __restrict__ qb,
                                                const u16* __restrict__ kb,
                                                const u16* __restrict__ vtb,
                                                u16* __restrict__ attn) {
  __shared__ __align__(16) u16 Qs[64 * 128];   // [q][d], chunk-swizzled
  __shared__ __align__(16) u16 Ks[64 * 128];   // [key][d], chunk-swizzled
  __shared__ __align__(16) u16 VTs[128 * 64];  // [d][key], chunk-swizzled
  __shared__ __align__(16) u16 Ps[64 * 72];    // [q][key], +8 pad
  __shared__ float Lred[128];

  const int t = threadIdx.x, lane = t & 63, w = t >> 6;
  const int c = lane & 15, quad = lane >> 4;
  const int q0 = blockIdx.x * 64;
  const int bh = blockIdx.y;
  const int b = bh >> 5, hq = bh & 31;
  const int kvp = b * 8 + (hq >> 2);
  const u16* qp = qb + (size_t)bh * (2048 * 128);
  const u16* kp = kb + (size_t)kvp * (2048 * 128);
  const u16* vp = vtb + (size_t)kvp * (128 * 2048);

  {  // stage Q once: wave covers 4 rows/instr (16 chunks of 16B per 128-d row)
    const int row_in = lane >> 4, ch = lane & 15;
#pragma unroll
    for (int i = 0; i < 4; ++i) {
      const int row = w * 4 + i * 16 + row_in;
      const int g = ch ^ (row & 15);
      load_lds16(qp + (size_t)(q0 + row) * 128 + g * 8, &Qs[(w * 4 + i * 16) * 128]);
    }
  }

  const int skh = (w & 1) * 32;   // wave's key offset in S^T
  const int sqh = (w >> 1) * 32;  // wave's query offset in S^T

  f32x4 oacc[8];
#pragma unroll
  for (int j = 0; j < 8; ++j)
#pragma unroll
    for (int r = 0; r < 4; ++r) oacc[j][r] = 0.0f;
  float lpart0 = 0.0f, lpart1 = 0.0f;

  int t0 = q0 - 1023;
  if (t0 < 0) t0 = 0;
  t0 = (t0 >> 6) << 6;

  for (int kv0 = t0; kv0 <= q0; kv0 += 64) {
    __syncthreads();  // previous iteration done reading Ks/VTs/Ps
    {
      const int row_in = lane >> 4, ch = lane & 15;
#pragma unroll
      for (int i = 0; i < 4; ++i) {
        const int row = w * 4 + i * 16 + row_in;
        const int g = ch ^ (row & 15);
        load_lds16(kp + (size_t)(kv0 + row) * 128 + g * 8, &Ks[(w * 4 + i * 16) * 128]);
      }
      const int drow = lane >> 3, ch8 = lane & 7;
#pragma unroll
      for (int i = 0; i < 4; ++i) {
        const int dd = w * 8 + i * 32 + drow;
        const int g = ch8 ^ (dd & 7);
        load_lds16(vp + (size_t)dd * 2048 + kv0 + g * 8, &VTs[(w * 8 + i * 32) * 64]);
      }
    }
    __syncthreads();  // staging complete

    // ---- S^T = K * Q^T : wave computes 32 keys x 32 queries
    f32x4 sacc[2][2];
#pragma unroll
    for (int im = 0; im < 2; ++im)
#pragma unroll
      for (int jn = 0; jn < 2; ++jn)
#pragma unroll
        for (int r = 0; r < 4; ++r) sacc[im][jn][r] = 0.0f;

#pragma unroll
    for (int ks = 0; ks < 4; ++ks) {
      bf16x8 af[2], bfr[2];
#pragma unroll
      for (int im = 0; im < 2; ++im) {
        const int key = skh + im * 16 + c;
        const int ch = (ks * 4 + quad) ^ (key & 15);
        af[im] = *(const bf16x8*)&Ks[key * 128 + ch * 8];
      }
#pragma unroll
      for (int jn = 0; jn < 2; ++jn) {
        const int q = sqh + jn * 16 + c;
        const int ch = (ks * 4 + quad) ^ (q & 15);
        bfr[jn] = *(const bf16x8*)&Qs[q * 128 + ch * 8];
      }
#pragma unroll
      for (int im = 0; im < 2; ++im)
#pragma unroll
        for (int jn = 0; jn < 2; ++jn)
          sacc[im][jn] = __builtin_amdgcn_mfma_f32_16x16x32_bf16(af[im], bfr[jn], sacc[im][jn], 0, 0, 0);
    }

    // ---- softcap + mask + exp; pack 4 consecutive keys -> one b64 write
#pragma unroll
    for (int im = 0; im < 2; ++im) {
#pragma unroll
      for (int jn = 0; jn < 2; ++jn) {
        const int i_glob = q0 + sqh + jn * 16 + c;
        const int j_base = kv0 + skh + im * 16 + quad * 4;
        float psum = 0.0f;
        u16 pr[4];
#pragma unroll
        for (int r = 0; r < 4; ++r) {
          const int j_glob = j_base + r;
          const float s = sacc[im][jn][r];
          const float e2 = __expf(s * 0.04f);        // e^(2s/50)
          const float cap = 50.0f * (1.0f - 2.0f / (e2 + 1.0f));
          const bool valid = (j_glob <= i_glob) && (i_glob - j_glob < 1024);
          const float p = valid ? __expf(cap) : 0.0f;
          psum += p;
          pr[r] = f2bf(p);
        }
        if (jn == 0) lpart0 += psum; else lpart1 += psum;
        ushort4 pkv;
        pkv.x = pr[0]; pkv.y = pr[1]; pkv.z = pr[2]; pkv.w = pr[3];
        const int qrow = sqh + jn * 16 + c;
        *(ushort4*)&Ps[qrow * 72 + skh + im * 16 + quad * 4] = pkv;
      }
    }
    __syncthreads();  // Ps visible to all waves

    // ---- PV: wave computes 16 queries x 128 d; A=P[q][key], B=V^T[d][key]
#pragma unroll
    for (int ks = 0; ks < 2; ++ks) {
      const bf16x8 pf = *(const bf16x8*)&Ps[(w * 16 + c) * 72 + ks * 32 + quad * 8];
#pragma unroll
      for (int jn = 0; jn < 8; ++jn) {
        const int dd = jn * 16 + c;
        const int ch = (ks * 4 + quad) ^ (dd & 7);
        const bf16x8 vf = *(const bf16x8*)&VTs[dd * 64 + ch * 8];
        oacc[jn] = __builtin_amdgcn_mfma_f32_16x16x32_bf16(pf, vf, oacc[jn], 0, 0, 0);
      }
    }
  }

  // ---- final: cross-quad + cross-wave lsum reduce, divide, store
  lpart0 += __shfl_xor(lpart0, 16); lpart0 += __shfl_xor(lpart0, 32);
  lpart1 += __shfl_xor(lpart1, 16); lpart1 += __shfl_xor(lpart1, 32);
  if (lane < 16) {
    Lred[(w & 1) * 64 + sqh + lane] = lpart0;
    Lred[(w & 1) * 64 + sqh + 16 + lane] = lpart1;
  }
  __syncthreads();
  float rl[4];
#pragma unroll
  for (int r = 0; r < 4; ++r) {
    const int q = w * 16 + quad * 4 + r;
    rl[r] = 1.0f / (Lred[q] + Lred[64 + q]);
  }
  const size_t obase = ((size_t)(b * 2048 + q0 + w * 16)) * 4096 + hq * 128;
#pragma unroll
  for (int jn = 0; jn < 8; ++jn) {
#pragma unroll
    for (int r = 0; r < 4; ++r) {
      const int q_in = quad * 4 + r;
      attn[obase + (size_t)q_in * 4096 + jn * 16 + c] = f2bf(oacc[jn][r] * rl[r]);
    }
  }
}

// ---------------------------------------------------------------- launch
extern "C" void kernel_launch(void* const* d_in, const int* in_sizes, int n_in,
                              void* d_out, int out_size, void* d_ws, size_t ws_size,
                              hipStream_t stream) {
  (void)in_sizes; (void)n_in; (void)out_size; (void)ws_size;
  const float* x  = (const float*)d_in[0];
  const float* Wq = (const float*)d_in[1];
  const float* Wk = (const float*)d_in[2];
  const float* Wv = (const float*)d_in[3];
  const float* Wo = (const float*)d_in[4];
  float* out = (float*)d_out;
  char* ws = (char*)d_ws;

  u16* xb    = (u16*)(ws + 0);
  u16* vtb   = (u16*)(ws + 0);             // reuses xb region (xb dead after GEMM1)
  u16* WqkvT = (u16*)(ws + 33554432ULL);
  u16* qb    = (u16*)(ws + 33554432ULL);   // q/k/v reuse WqkvT region (dead after GEMM1)
  u16* kb    = (u16*)(ws + 67108864ULL);
  u16* vb    = (u16*)(ws + 75497472ULL);
  u16* WoT   = (u16*)(ws + 83886080ULL);   // persistent
  u16* qkvr  = (u16*)(ws + 117440512ULL);
  u16* attnb = (u16*)(ws + 117440512ULL);  // reuses qkv_raw region (dead after postprocess)

  cast_f32_bf16<<<8192, 256, 0, stream>>>(x, xb);
  transpose_cast_f32_bf16<<<dim3(128, 128), 256, 0, stream>>>(Wq, WqkvT, 4096, 4096);
  transpose_cast_f32_bf16<<<dim3(32, 128), 256, 0, stream>>>(Wk, WqkvT + (size_t)4096 * 4096, 4096, 1024);
  transpose_cast_f32_bf16<<<dim3(32, 128), 256, 0, stream>>>(Wv, WqkvT + (size_t)5120 * 4096, 4096, 1024);
  transpose_cast_f32_bf16<<<dim3(128, 128), 256, 0, stream>>>(Wo, WoT, 4096, 4096);

  gemm_bt<1><<<dim3(48, 32), 256, 0, stream>>>(xb, WqkvT, (void*)qkvr, 4096, 6144, 4096);
  qkv_post<<<49152, 256, 0, stream>>>(qkvr, qb, kb, vb);
  transpose_v<<<dim3(64, 4, 16), 256, 0, stream>>>(vb, vtb);
  attn_fwd<<<dim3(32, 64), 256, 0, stream>>>(qb, kb, vtb, attnb);
  gemm_bt<0><<<dim3(32, 32), 256, 0, stream>>>(attnb, WoT, (void*)out, 4096, 4096, 4096);
}

// Round 2
// 919.959 us; speedup vs baseline: 1.0258x; 1.0258x over previous
//
#include <hip/hip_runtime.h>

// Fused GQA attention layer for MI355X (gfx950).
// B=2 S=2048 E=4096 HQ=32 HKV=8 D=128 WINDOW=1024 SOFT_CAP=50 Q_PRE_ATTN=128
//
// Pipeline (all bf16 MFMA 16x16x32):
//   1. cast x -> bf16; transpose-cast Wq|Wk|Wv -> WqkvT[6144][4096], Wo -> WoT[4096][4096]
//   2. GEMM1: qkv_raw[4096][6144] = xb @ WqkvT^T            (m97-style, global_load_lds w16)
//   3. postprocess: l2norm + RoPE + q-scale -> q/k planes, v natural + v^T planes
//   4. flash attention (S^T = K*Q^T trick, fixed-max softmax since softcap bounds logits)
//   5. GEMM2: out = attn @ WoT^T  (fp32 out)
//
// R2: XOR chunk swizzle in gemm_bt LDS (stored chunk = k ^ ((row>>1)&3)), applied on
//     the GLOBAL address at staging so global_load_lds lane-contiguity is preserved.
//     Removes the 2.5e7 SQ_LDS_BANK_CONFLICT (frag b128 reads now hit all 8 bank
//     groups, 8 accesses/bank = floor).
//
// Workspace layout (total 167,772,160 B = 160 MiB, regions reused over time):
//   [0,        33.5M)  xb        -> later vtb
//   [33.5M,    83.9M)  WqkvT     -> later qb|kb|vb
//   [83.9M,   117.4M)  WoT       (persistent)
//   [117.4M,  167.8M)  qkv_raw   -> later attn

typedef unsigned short u16;
typedef unsigned int   u32;
typedef __bf16 bf16x8 __attribute__((ext_vector_type(8)));
typedef float  f32x4  __attribute__((ext_vector_type(4)));

typedef __attribute__((address_space(1))) void* gas_ptr;
typedef __attribute__((address_space(3))) void* las_ptr;

__device__ __forceinline__ void load_lds16(const void* g, void* l) {
  // async global->LDS, 16B/lane; LDS dest = wave-uniform base + lane*16
  __builtin_amdgcn_global_load_lds((gas_ptr)g, (las_ptr)l, 16, 0, 0);
}

__device__ __forceinline__ u16 f2bf(float f) {
  u32 u = __builtin_bit_cast(u32, f);
  u += 0x7fffu + ((u >> 16) & 1u);   // RNE
  return (u16)(u >> 16);
}
__device__ __forceinline__ float bf2f(u16 h) {
  u32 u = ((u32)h) << 16;
  return __builtin_bit_cast(float, u);
}

// ---------------------------------------------------------------- cast x
__global__ __launch_bounds__(256) void cast_f32_bf16(const float* __restrict__ src,
                                                     u16* __restrict__ dst) {
  size_t i = ((size_t)blockIdx.x * 256 + threadIdx.x) * 8;
  float4 a = *(const float4*)(src + i);
  float4 b = *(const float4*)(src + i + 4);
  uint4 o;
  o.x = (u32)f2bf(a.x) | ((u32)f2bf(a.y) << 16);
  o.y = (u32)f2bf(a.z) | ((u32)f2bf(a.w) << 16);
  o.z = (u32)f2bf(b.x) | ((u32)f2bf(b.y) << 16);
  o.w = (u32)f2bf(b.z) | ((u32)f2bf(b.w) << 16);
  *(uint4*)(dst + i) = o;
}

// ------------------------------------------------- transpose-cast fp32->bf16
// src [R][C] row-major -> dst [C][R] row-major. R,C multiples of 32.
__global__ __launch_bounds__(256) void transpose_cast_f32_bf16(
    const float* __restrict__ src, u16* __restrict__ dst, int R, int C) {
  __shared__ float tile[32][33];
  const int tx = threadIdx.x & 31, ty = threadIdx.x >> 5;  // ty 0..7
  const int r0 = blockIdx.y * 32, c0 = blockIdx.x * 32;
#pragma unroll
  for (int i = 0; i < 4; ++i)
    tile[ty + i * 8][tx] = src[(size_t)(r0 + ty + i * 8) * C + (c0 + tx)];
  __syncthreads();
#pragma unroll
  for (int i = 0; i < 4; ++i)
    dst[(size_t)(c0 + ty + i * 8) * R + (r0 + tx)] = f2bf(tile[tx][ty + i * 8]);
}

// ------------------------------------------------- bf16 transpose for v planes
// per plane: src [2048][128] -> dst [128][2048]; grid (64, 4, 16planes)
__global__ __launch_bounds__(256) void transpose_v(const u16* __restrict__ src,
                                                   u16* __restrict__ dst) {
  __shared__ u16 tile[32][34];
  const int plane = blockIdx.z;
  const u16* s = src + (size_t)plane * 2048 * 128;
  u16* d = dst + (size_t)plane * 2048 * 128;
  const int tx = threadIdx.x & 31, ty = threadIdx.x >> 5;
  const int r0 = blockIdx.x * 32, c0 = blockIdx.y * 32;
#pragma unroll
  for (int i = 0; i < 4; ++i)
    tile[ty + i * 8][tx] = s[(size_t)(r0 + ty + i * 8) * 128 + (c0 + tx)];
  __syncthreads();
#pragma unroll
  for (int i = 0; i < 4; ++i)
    d[(size_t)(c0 + ty + i * 8) * 2048 + (r0 + tx)] = tile[tx][ty + i * 8];
}

// ---------------------------------------------------------------- GEMM (m97-style)
// C[M][N] = A[M][K] @ Bt[N][K]^T ; A,Bt bf16 row-major; 128x128 tile, BK=32,
// 4 waves, each 64x64 (4x4 of 16x16x32 MFMA). global_load_lds width 16.
// LDS tiles XOR-chunk-swizzled: logical chunk k (of 4 per 64B row) stored at
// s = k ^ ((row>>1)&3). Swizzle applied on global src addr at staging.
template <int OUT_BF16>
__global__ __launch_bounds__(256) void gemm_bt(const u16* __restrict__ A,
                                               const u16* __restrict__ Bt,
                                               void* __restrict__ Cout,
                                               int M, int N, int K) {
  __shared__ __align__(16) u16 As[128 * 32];
  __shared__ __align__(16) u16 Bs[128 * 32];
  const int t = threadIdx.x;
  const int lane = t & 63, w = t >> 6;
  const int c = lane & 15, quad = lane >> 4;
  const int m0 = blockIdx.y * 128, n0 = blockIdx.x * 128;
  const int wm = (w >> 1) * 64, wn = (w & 1) * 64;
  const int srow = lane >> 2;
  // stored chunk at LDS slot (row_local=lane>>2, s=lane&3) holds logical chunk
  // s ^ ((row>>1)&3) = (lane&3) ^ ((lane>>3)&3)  (w*16 and +64 offsets drop out)
  const int sch = ((lane & 3) ^ ((lane >> 3) & 3)) * 8;

  f32x4 acc[4][4];
#pragma unroll
  for (int i = 0; i < 4; ++i)
#pragma unroll
    for (int j = 0; j < 4; ++j)
#pragma unroll
      for (int r = 0; r < 4; ++r) acc[i][j][r] = 0.0f;

  const u16* Ab = A + (size_t)(m0 + w * 16 + srow) * K + sch;
  const u16* Bb = Bt + (size_t)(n0 + w * 16 + srow) * K + sch;
  const size_t row64 = (size_t)64 * K;
  u16* AsW = &As[(w * 16) * 32];
  u16* AsW2 = &As[(64 + w * 16) * 32];
  u16* BsW = &Bs[(w * 16) * 32];
  u16* BsW2 = &Bs[(64 + w * 16) * 32];

  for (int k0 = 0; k0 < K; k0 += 32) {
    __syncthreads();                       // previous tile's reads done
    load_lds16(Ab + k0, AsW);
    load_lds16(Ab + row64 + k0, AsW2);
    load_lds16(Bb + k0, BsW);
    load_lds16(Bb + row64 + k0, BsW2);
    __syncthreads();                       // vmcnt(0) drained before barrier
    bf16x8 af[4], bfr[4];
#pragma unroll
    for (int i = 0; i < 4; ++i) {
      const int row = wm + i * 16 + c;
      af[i] = *(const bf16x8*)&As[row * 32 + (quad ^ ((row >> 1) & 3)) * 8];
    }
#pragma unroll
    for (int j = 0; j < 4; ++j) {
      const int row = wn + j * 16 + c;
      bfr[j] = *(const bf16x8*)&Bs[row * 32 + (quad ^ ((row >> 1) & 3)) * 8];
    }
#pragma unroll
    for (int i = 0; i < 4; ++i)
#pragma unroll
      for (int j = 0; j < 4; ++j)
        acc[i][j] = __builtin_amdgcn_mfma_f32_16x16x32_bf16(af[i], bfr[j], acc[i][j], 0, 0, 0);
  }

#pragma unroll
  for (int i = 0; i < 4; ++i) {
#pragma unroll
    for (int j = 0; j < 4; ++j) {
      const int col = n0 + wn + j * 16 + c;
#pragma unroll
      for (int r = 0; r < 4; ++r) {
        const int row = m0 + wm + i * 16 + quad * 4 + r;  // C/D: row=quad*4+reg, col=lane&15
        if (OUT_BF16)
          ((u16*)Cout)[(size_t)row * N + col] = f2bf(acc[i][j][r]);
        else
          ((float*)Cout)[(size_t)row * N + col] = acc[i][j][r];
      }
    }
  }
}

// ---------------------------------------------------------------- qkv postprocess
// one wave per (row, head-vector). hh: 0..31 q, 32..39 k, 40..47 v.
// lane i holds d=i and d=i+64 (the RoPE pair). l2norm via wave shuffle reduce.
__global__ __launch_bounds__(256) void qkv_post(const u16* __restrict__ raw,
                                                u16* __restrict__ qb,
                                                u16* __restrict__ kb,
                                                u16* __restrict__ vb) {
  const int t = threadIdx.x, lane = t & 63, w = t >> 6;
  const int idx = blockIdx.x * 4 + w;
  const int row = idx / 48, hh = idx - row * 48;
  const int b = row >> 11, pos = row & 2047;
  const u16* base = raw + (size_t)row * 6144 + hh * 128;
  const u16 r1 = base[lane], r2 = base[lane + 64];

  if (hh >= 40) {  // v: pass-through (no norm/rope)
    u16* dst = vb + ((size_t)((b * 8 + (hh - 40)) * 2048 + pos)) * 128;
    dst[lane] = r1;
    dst[lane + 64] = r2;
    return;
  }
  float v1 = bf2f(r1), v2 = bf2f(r2);
  float ss = v1 * v1 + v2 * v2;
#pragma unroll
  for (int off = 32; off >= 1; off >>= 1) ss += __shfl_xor(ss, off);
  const float rn = rsqrtf(ss * (1.0f / 128.0f) + 1e-6f);
  const float n1 = v1 * rn, n2 = v2 * rn;
  const float fr = exp2f(-(float)lane * 0.20762050593046f);  // 10000^(-lane/64)
  const float ang = (float)pos * fr;
  float sn, cs;
  sincosf(ang, &sn, &cs);
  float o1 = n1 * cs - n2 * sn;
  float o2 = n2 * cs + n1 * sn;
  u16* dst;
  if (hh < 32) {
    const float as_ = logf(floorf((float)(pos + 1) * (1.0f / 8192.0f)) + 1.0f) * 0.1f + 1.0f;
    const float sc = 0.088388347648318447f * as_;  // 128^-0.5 * attn_scale
    o1 *= sc;
    o2 *= sc;
    dst = qb + ((size_t)((b * 32 + hh) * 2048 + pos)) * 128;
  } else {
    dst = kb + ((size_t)((b * 8 + (hh - 32)) * 2048 + pos)) * 128;
  }
  dst[lane] = f2bf(o1);
  dst[lane + 64] = f2bf(o2);
}

// ---------------------------------------------------------------- flash attention
// Block: one (b, hq, 64-query tile); 4 waves. KV tiles of 64 keys.
// S^T = K*Q^T so C-layout rows are KEYS -> packed ds_write_b64 into key-contiguous
// P[q][key] (stride 72 shorts). Softcap bounds logits to +-50 -> fixed-max softmax.
// Q/K/VT LDS tiles use XOR chunk swizzle (applied on global addr so
// global_load_lds lane-contiguity is preserved) -> frag reads 2-way (free).
__global__ __launch_bounds__(256) void attn_fwd(const u16* __restrict__ qb,
                                                const u16* __restrict__ kb,
                                                const u16* __restrict__ vtb,
                                                u16* __restrict__ attn) {
  __shared__ __align__(16) u16 Qs[64 * 128];   // [q][d], chunk-swizzled
  __shared__ __align__(16) u16 Ks[64 * 128];   // [key][d], chunk-swizzled
  __shared__ __align__(16) u16 VTs[128 * 64];  // [d][key], chunk-swizzled
  __shared__ __align__(16) u16 Ps[64 * 72];    // [q][key], +8 pad
  __shared__ float Lred[128];

  const int t = threadIdx.x, lane = t & 63, w = t >> 6;
  const int c = lane & 15, quad = lane >> 4;
  const int q0 = blockIdx.x * 64;
  const int bh = blockIdx.y;
  const int b = bh >> 5, hq = bh & 31;
  const int kvp = b * 8 + (hq >> 2);
  const u16* qp = qb + (size_t)bh * (2048 * 128);
  const u16* kp = kb + (size_t)kvp * (2048 * 128);
  const u16* vp = vtb + (size_t)kvp * (128 * 2048);

  {  // stage Q once: wave covers 4 rows/instr (16 chunks of 16B per 128-d row)
    const int row_in = lane >> 4, ch = lane & 15;
#pragma unroll
    for (int i = 0; i < 4; ++i) {
      const int row = w * 4 + i * 16 + row_in;
      const int g = ch ^ (row & 15);
      load_lds16(qp + (size_t)(q0 + row) * 128 + g * 8, &Qs[(w * 4 + i * 16) * 128]);
    }
  }

  const int skh = (w & 1) * 32;   // wave's key offset in S^T
  const int sqh = (w >> 1) * 32;  // wave's query offset in S^T

  f32x4 oacc[8];
#pragma unroll
  for (int j = 0; j < 8; ++j)
#pragma unroll
    for (int r = 0; r < 4; ++r) oacc[j][r] = 0.0f;
  float lpart0 = 0.0f, lpart1 = 0.0f;

  int t0 = q0 - 1023;
  if (t0 < 0) t0 = 0;
  t0 = (t0 >> 6) << 6;

  for (int kv0 = t0; kv0 <= q0; kv0 += 64) {
    __syncthreads();  // previous iteration done reading Ks/VTs/Ps
    {
      const int row_in = lane >> 4, ch = lane & 15;
#pragma unroll
      for (int i = 0; i < 4; ++i) {
        const int row = w * 4 + i * 16 + row_in;
        const int g = ch ^ (row & 15);
        load_lds16(kp + (size_t)(kv0 + row) * 128 + g * 8, &Ks[(w * 4 + i * 16) * 128]);
      }
      const int drow = lane >> 3, ch8 = lane & 7;
#pragma unroll
      for (int i = 0; i < 4; ++i) {
        const int dd = w * 8 + i * 32 + drow;
        const int g = ch8 ^ (dd & 7);
        load_lds16(vp + (size_t)dd * 2048 + kv0 + g * 8, &VTs[(w * 8 + i * 32) * 64]);
      }
    }
    __syncthreads();  // staging complete

    // ---- S^T = K * Q^T : wave computes 32 keys x 32 queries
    f32x4 sacc[2][2];
#pragma unroll
    for (int im = 0; im < 2; ++im)
#pragma unroll
      for (int jn = 0; jn < 2; ++jn)
#pragma unroll
        for (int r = 0; r < 4; ++r) sacc[im][jn][r] = 0.0f;

#pragma unroll
    for (int ks = 0; ks < 4; ++ks) {
      bf16x8 af[2], bfr[2];
#pragma unroll
      for (int im = 0; im < 2; ++im) {
        const int key = skh + im * 16 + c;
        const int ch = (ks * 4 + quad) ^ (key & 15);
        af[im] = *(const bf16x8*)&Ks[key * 128 + ch * 8];
      }
#pragma unroll
      for (int jn = 0; jn < 2; ++jn) {
        const int q = sqh + jn * 16 + c;
        const int ch = (ks * 4 + quad) ^ (q & 15);
        bfr[jn] = *(const bf16x8*)&Qs[q * 128 + ch * 8];
      }
#pragma unroll
      for (int im = 0; im < 2; ++im)
#pragma unroll
        for (int jn = 0; jn < 2; ++jn)
          sacc[im][jn] = __builtin_amdgcn_mfma_f32_16x16x32_bf16(af[im], bfr[jn], sacc[im][jn], 0, 0, 0);
    }

    // ---- softcap + mask + exp; pack 4 consecutive keys -> one b64 write
#pragma unroll
    for (int im = 0; im < 2; ++im) {
#pragma unroll
      for (int jn = 0; jn < 2; ++jn) {
        const int i_glob = q0 + sqh + jn * 16 + c;
        const int j_base = kv0 + skh + im * 16 + quad * 4;
        float psum = 0.0f;
        u16 pr[4];
#pragma unroll
        for (int r = 0; r < 4; ++r) {
          const int j_glob = j_base + r;
          const float s = sacc[im][jn][r];
          const float e2 = __expf(s * 0.04f);        // e^(2s/50)
          const float cap = 50.0f * (1.0f - 2.0f / (e2 + 1.0f));
          const bool valid = (j_glob <= i_glob) && (i_glob - j_glob < 1024);
          const float p = valid ? __expf(cap) : 0.0f;
          psum += p;
          pr[r] = f2bf(p);
        }
        if (jn == 0) lpart0 += psum; else lpart1 += psum;
        ushort4 pkv;
        pkv.x = pr[0]; pkv.y = pr[1]; pkv.z = pr[2]; pkv.w = pr[3];
        const int qrow = sqh + jn * 16 + c;
        *(ushort4*)&Ps[qrow * 72 + skh + im * 16 + quad * 4] = pkv;
      }
    }
    __syncthreads();  // Ps visible to all waves

    // ---- PV: wave computes 16 queries x 128 d; A=P[q][key], B=V^T[d][key]
#pragma unroll
    for (int ks = 0; ks < 2; ++ks) {
      const bf16x8 pf = *(const bf16x8*)&Ps[(w * 16 + c) * 72 + ks * 32 + quad * 8];
#pragma unroll
      for (int jn = 0; jn < 8; ++jn) {
        const int dd = jn * 16 + c;
        const int ch = (ks * 4 + quad) ^ (dd & 7);
        const bf16x8 vf = *(const bf16x8*)&VTs[dd * 64 + ch * 8];
        oacc[jn] = __builtin_amdgcn_mfma_f32_16x16x32_bf16(pf, vf, oacc[jn], 0, 0, 0);
      }
    }
  }

  // ---- final: cross-quad + cross-wave lsum reduce, divide, store
  lpart0 += __shfl_xor(lpart0, 16); lpart0 += __shfl_xor(lpart0, 32);
  lpart1 += __shfl_xor(lpart1, 16); lpart1 += __shfl_xor(lpart1, 32);
  if (lane < 16) {
    Lred[(w & 1) * 64 + sqh + lane] = lpart0;
    Lred[(w & 1) * 64 + sqh + 16 + lane] = lpart1;
  }
  __syncthreads();
  float rl[4];
#pragma unroll
  for (int r = 0; r < 4; ++r) {
    const int q = w * 16 + quad * 4 + r;
    rl[r] = 1.0f / (Lred[q] + Lred[64 + q]);
  }
  const size_t obase = ((size_t)(b * 2048 + q0 + w * 16)) * 4096 + hq * 128;
#pragma unroll
  for (int jn = 0; jn < 8; ++jn) {
#pragma unroll
    for (int r = 0; r < 4; ++r) {
      const int q_in = quad * 4 + r;
      attn[obase + (size_t)q_in * 4096 + jn * 16 + c] = f2bf(oacc[jn][r] * rl[r]);
    }
  }
}

// ---------------------------------------------------------------- launch
extern "C" void kernel_launch(void* const* d_in, const int* in_sizes, int n_in,
                              void* d_out, int out_size, void* d_ws, size_t ws_size,
                              hipStream_t stream) {
  (void)in_sizes; (void)n_in; (void)out_size; (void)ws_size;
  const float* x  = (const float*)d_in[0];
  const float* Wq = (const float*)d_in[1];
  const float* Wk = (const float*)d_in[2];
  const float* Wv = (const float*)d_in[3];
  const float* Wo = (const float*)d_in[4];
  float* out = (float*)d_out;
  char* ws = (char*)d_ws;

  u16* xb    = (u16*)(ws + 0);
  u16* vtb   = (u16*)(ws + 0);             // reuses xb region (xb dead after GEMM1)
  u16* WqkvT = (u16*)(ws + 33554432ULL);
  u16* qb    = (u16*)(ws + 33554432ULL);   // q/k/v reuse WqkvT region (dead after GEMM1)
  u16* kb    = (u16*)(ws + 67108864ULL);
  u16* vb    = (u16*)(ws + 75497472ULL);
  u16* WoT   = (u16*)(ws + 83886080ULL);   // persistent
  u16* qkvr  = (u16*)(ws + 117440512ULL);
  u16* attnb = (u16*)(ws + 117440512ULL);  // reuses qkv_raw region (dead after postprocess)

  cast_f32_bf16<<<8192, 256, 0, stream>>>(x, xb);
  transpose_cast_f32_bf16<<<dim3(128, 128), 256, 0, stream>>>(Wq, WqkvT, 4096, 4096);
  transpose_cast_f32_bf16<<<dim3(32, 128), 256, 0, stream>>>(Wk, WqkvT + (size_t)4096 * 4096, 4096, 1024);
  transpose_cast_f32_bf16<<<dim3(32, 128), 256, 0, stream>>>(Wv, WqkvT + (size_t)5120 * 4096, 4096, 1024);
  transpose_cast_f32_bf16<<<dim3(128, 128), 256, 0, stream>>>(Wo, WoT, 4096, 4096);

  gemm_bt<1><<<dim3(48, 32), 256, 0, stream>>>(xb, WqkvT, (void*)qkvr, 4096, 6144, 4096);
  qkv_post<<<49152, 256, 0, stream>>>(qkvr, qb, kb, vb);
  transpose_v<<<dim3(64, 4, 16), 256, 0, stream>>>(vb, vtb);
  attn_fwd<<<dim3(32, 64), 256, 0, stream>>>(qb, kb, vtb, attnb);
  gemm_bt<0><<<dim3(32, 32), 256, 0, stream>>>(attnb, WoT, (void*)out, 4096, 4096, 4096);
}

// Round 4
// 816.313 us; speedup vs baseline: 1.1560x; 1.1270x over previous
//
#include <hip/hip_runtime.h>

// Fused GQA attention layer for MI355X (gfx950).
// B=2 S=2048 E=4096 HQ=32 HKV=8 D=128 WINDOW=1024 SOFT_CAP=50 Q_PRE_ATTN=128
//
// R4: attention — each wave owns 16 queries end-to-end.
//   * Q frags in registers; K/VT staged via global_load_lds (XOR chunk swizzle).
//   * P transposed C-layout -> A-layout via WAVE-PRIVATE LDS round trip
//     (4 ds_write_b64 + 2 ds_read_b128, no barriers — replaces R3's broken
//     bpermute whose source-operand selection couldn't express the transform).
//   * LDS 40KB => 4 blocks/CU (launch_bounds(256,4)); 2 barriers/KV-tile.
//   * softmax: fixed-max (softcap bounds logits), poly tanh, masks hoisted.
//
// Workspace layout (160 MiB, regions reused over time):
//   [0,        33.5M)  xb        -> later vtb
//   [33.5M,    83.9M)  WqkvT     -> later qb|kb|vb
//   [83.9M,   117.4M)  WoT       (persistent)
//   [117.4M,  167.8M)  qkv_raw   -> later attn

typedef unsigned short u16;
typedef unsigned int   u32;
typedef __bf16 bf16x8 __attribute__((ext_vector_type(8)));
typedef float  f32x4  __attribute__((ext_vector_type(4)));

typedef __attribute__((address_space(1))) void* gas_ptr;
typedef __attribute__((address_space(3))) void* las_ptr;

__device__ __forceinline__ void load_lds16(const void* g, void* l) {
  __builtin_amdgcn_global_load_lds((gas_ptr)g, (las_ptr)l, 16, 0, 0);
}

__device__ __forceinline__ u16 f2bf(float f) {
  u32 u = __builtin_bit_cast(u32, f);
  u += 0x7fffu + ((u >> 16) & 1u);   // RNE
  return (u16)(u >> 16);
}
__device__ __forceinline__ float bf2f(u16 h) {
  u32 u = ((u32)h) << 16;
  return __builtin_bit_cast(float, u);
}
// truncate-pack two fp32 -> bf16 pair (low = a, high = b)
__device__ __forceinline__ u32 pack_trunc(float a, float b) {
  return (__builtin_bit_cast(u32, a) >> 16) | (__builtin_bit_cast(u32, b) & 0xffff0000u);
}

// ---------------------------------------------------------------- cast x
__global__ __launch_bounds__(256) void cast_f32_bf16(const float* __restrict__ src,
                                                     u16* __restrict__ dst) {
  size_t i = ((size_t)blockIdx.x * 256 + threadIdx.x) * 8;
  float4 a = *(const float4*)(src + i);
  float4 b = *(const float4*)(src + i + 4);
  uint4 o;
  o.x = (u32)f2bf(a.x) | ((u32)f2bf(a.y) << 16);
  o.y = (u32)f2bf(a.z) | ((u32)f2bf(a.w) << 16);
  o.z = (u32)f2bf(b.x) | ((u32)f2bf(b.y) << 16);
  o.w = (u32)f2bf(b.z) | ((u32)f2bf(b.w) << 16);
  *(uint4*)(dst + i) = o;
}

// ------------------------------------------------- transpose-cast fp32->bf16
__global__ __launch_bounds__(256) void transpose_cast_f32_bf16(
    const float* __restrict__ src, u16* __restrict__ dst, int R, int C) {
  __shared__ float tile[32][33];
  const int tx = threadIdx.x & 31, ty = threadIdx.x >> 5;
  const int r0 = blockIdx.y * 32, c0 = blockIdx.x * 32;
#pragma unroll
  for (int i = 0; i < 4; ++i)
    tile[ty + i * 8][tx] = src[(size_t)(r0 + ty + i * 8) * C + (c0 + tx)];
  __syncthreads();
#pragma unroll
  for (int i = 0; i < 4; ++i)
    dst[(size_t)(c0 + ty + i * 8) * R + (r0 + tx)] = f2bf(tile[tx][ty + i * 8]);
}

// ------------------------------------------------- bf16 transpose for v planes
__global__ __launch_bounds__(256) void transpose_v(const u16* __restrict__ src,
                                                   u16* __restrict__ dst) {
  __shared__ u16 tile[32][34];
  const int plane = blockIdx.z;
  const u16* s = src + (size_t)plane * 2048 * 128;
  u16* d = dst + (size_t)plane * 2048 * 128;
  const int tx = threadIdx.x & 31, ty = threadIdx.x >> 5;
  const int r0 = blockIdx.x * 32, c0 = blockIdx.y * 32;
#pragma unroll
  for (int i = 0; i < 4; ++i)
    tile[ty + i * 8][tx] = s[(size_t)(r0 + ty + i * 8) * 128 + (c0 + tx)];
  __syncthreads();
#pragma unroll
  for (int i = 0; i < 4; ++i)
    d[(size_t)(c0 + ty + i * 8) * 2048 + (r0 + tx)] = tile[tx][ty + i * 8];
}

// ---------------------------------------------------------------- GEMM (m97-style)
// C[M][N] = A[M][K] @ Bt[N][K]^T ; 128x128 tile, BK=32, XOR-chunk-swizzled LDS.
template <int OUT_BF16>
__global__ __launch_bounds__(256) void gemm_bt(const u16* __restrict__ A,
                                               const u16* __restrict__ Bt,
                                               void* __restrict__ Cout,
                                               int M, int N, int K) {
  __shared__ __align__(16) u16 As[128 * 32];
  __shared__ __align__(16) u16 Bs[128 * 32];
  const int t = threadIdx.x;
  const int lane = t & 63, w = t >> 6;
  const int c = lane & 15, quad = lane >> 4;
  const int m0 = blockIdx.y * 128, n0 = blockIdx.x * 128;
  const int wm = (w >> 1) * 64, wn = (w & 1) * 64;
  const int srow = lane >> 2;
  const int sch = ((lane & 3) ^ ((lane >> 3) & 3)) * 8;

  f32x4 acc[4][4];
#pragma unroll
  for (int i = 0; i < 4; ++i)
#pragma unroll
    for (int j = 0; j < 4; ++j)
#pragma unroll
      for (int r = 0; r < 4; ++r) acc[i][j][r] = 0.0f;

  const u16* Ab = A + (size_t)(m0 + w * 16 + srow) * K + sch;
  const u16* Bb = Bt + (size_t)(n0 + w * 16 + srow) * K + sch;
  const size_t row64 = (size_t)64 * K;
  u16* AsW = &As[(w * 16) * 32];
  u16* AsW2 = &As[(64 + w * 16) * 32];
  u16* BsW = &Bs[(w * 16) * 32];
  u16* BsW2 = &Bs[(64 + w * 16) * 32];

  for (int k0 = 0; k0 < K; k0 += 32) {
    __syncthreads();
    load_lds16(Ab + k0, AsW);
    load_lds16(Ab + row64 + k0, AsW2);
    load_lds16(Bb + k0, BsW);
    load_lds16(Bb + row64 + k0, BsW2);
    __syncthreads();
    bf16x8 af[4], bfr[4];
#pragma unroll
    for (int i = 0; i < 4; ++i) {
      const int row = wm + i * 16 + c;
      af[i] = *(const bf16x8*)&As[row * 32 + (quad ^ ((row >> 1) & 3)) * 8];
    }
#pragma unroll
    for (int j = 0; j < 4; ++j) {
      const int row = wn + j * 16 + c;
      bfr[j] = *(const bf16x8*)&Bs[row * 32 + (quad ^ ((row >> 1) & 3)) * 8];
    }
#pragma unroll
    for (int i = 0; i < 4; ++i)
#pragma unroll
      for (int j = 0; j < 4; ++j)
        acc[i][j] = __builtin_amdgcn_mfma_f32_16x16x32_bf16(af[i], bfr[j], acc[i][j], 0, 0, 0);
  }

#pragma unroll
  for (int i = 0; i < 4; ++i) {
#pragma unroll
    for (int j = 0; j < 4; ++j) {
      const int col = n0 + wn + j * 16 + c;
#pragma unroll
      for (int r = 0; r < 4; ++r) {
        const int row = m0 + wm + i * 16 + quad * 4 + r;
        if (OUT_BF16)
          ((u16*)Cout)[(size_t)row * N + col] = f2bf(acc[i][j][r]);
        else
          ((float*)Cout)[(size_t)row * N + col] = acc[i][j][r];
      }
    }
  }
}

// ---------------------------------------------------------------- qkv postprocess
__global__ __launch_bounds__(256) void qkv_post(const u16* __restrict__ raw,
                                                u16* __restrict__ qb,
                                                u16* __restrict__ kb,
                                                u16* __restrict__ vb) {
  const int t = threadIdx.x, lane = t & 63, w = t >> 6;
  const int idx = blockIdx.x * 4 + w;
  const int row = idx / 48, hh = idx - row * 48;
  const int b = row >> 11, pos = row & 2047;
  const u16* base = raw + (size_t)row * 6144 + hh * 128;
  const u16 r1 = base[lane], r2 = base[lane + 64];

  if (hh >= 40) {
    u16* dst = vb + ((size_t)((b * 8 + (hh - 40)) * 2048 + pos)) * 128;
    dst[lane] = r1;
    dst[lane + 64] = r2;
    return;
  }
  float v1 = bf2f(r1), v2 = bf2f(r2);
  float ss = v1 * v1 + v2 * v2;
#pragma unroll
  for (int off = 32; off >= 1; off >>= 1) ss += __shfl_xor(ss, off);
  const float rn = rsqrtf(ss * (1.0f / 128.0f) + 1e-6f);
  const float n1 = v1 * rn, n2 = v2 * rn;
  const float fr = exp2f(-(float)lane * 0.20762050593046f);  // 10000^(-lane/64)
  const float ang = (float)pos * fr;
  float sn, cs;
  sincosf(ang, &sn, &cs);
  float o1 = n1 * cs - n2 * sn;
  float o2 = n2 * cs + n1 * sn;
  u16* dst;
  if (hh < 32) {
    const float as_ = logf(floorf((float)(pos + 1) * (1.0f / 8192.0f)) + 1.0f) * 0.1f + 1.0f;
    const float sc = 0.088388347648318447f * as_;  // 128^-0.5 * attn_scale
    o1 *= sc;
    o2 *= sc;
    dst = qb + ((size_t)((b * 32 + hh) * 2048 + pos)) * 128;
  } else {
    dst = kb + ((size_t)((b * 8 + (hh - 32)) * 2048 + pos)) * 128;
  }
  dst[lane] = f2bf(o1);
  dst[lane + 64] = f2bf(o2);
}

// ---------------------------------------------------------------- flash attention
// Block: one (b, hq, 64-query tile); 4 waves; each wave owns 16 queries.
// Per KV tile: S^T = K*Q^T (A=K LDS, B=Q regs); fixed-max softmax w/ poly
// softcap; P -> wave-private LDS (write C-layout b64, read A-layout b128,
// XOR chunk swizzle, no barriers); PV with A=P, B=V^T(LDS). 2 barriers/iter.
__global__ __launch_bounds__(256, 4) void attn_fwd(const u16* __restrict__ qb,
                                                   const u16* __restrict__ kb,
                                                   const u16* __restrict__ vtb,
                                                   u16* __restrict__ attn) {
  __shared__ __align__(16) u16 Ks[64 * 128];    // [key][d], chunk-swizzled (16 chunks)
  __shared__ __align__(16) u16 VTs[128 * 64];   // [d][key], chunk-swizzled (8 chunks)
  __shared__ __align__(16) u16 Ps[4][16 * 64];  // per-wave [query][key], chunk-swizzled

  const int t = threadIdx.x, lane = t & 63, w = t >> 6;
  const int c = lane & 15, quad = lane >> 4;
  const int q0 = blockIdx.x * 64;
  const int bh = blockIdx.y;
  const int b = bh >> 5, hq = bh & 31;
  const int kvp = b * 8 + (hq >> 2);
  const u16* qp = qb + (size_t)bh * (2048 * 128);
  const u16* kp = kb + (size_t)kvp * (2048 * 128);
  const u16* vp = vtb + (size_t)kvp * (128 * 2048);
  u16* Psw = &Ps[w][0];

  // Q fragments in registers: wave's query = q0 + w*16 + c; qf[ks]: d=ks*32+quad*8..+7
  bf16x8 qf[4];
  {
    const u16* qrow = qp + (size_t)(q0 + w * 16 + c) * 128 + quad * 8;
#pragma unroll
    for (int ks = 0; ks < 4; ++ks) qf[ks] = *(const bf16x8*)(qrow + ks * 32);
  }

  f32x4 oacc[8];
#pragma unroll
  for (int j = 0; j < 8; ++j)
#pragma unroll
    for (int r = 0; r < 4; ++r) oacc[j][r] = 0.0f;
  float lsum = 0.0f;

  const int i_glob = q0 + w * 16 + c;

  int t0 = q0 - 1023;
  if (t0 < 0) t0 = 0;
  t0 = (t0 >> 6) << 6;

  for (int kv0 = t0; kv0 <= q0; kv0 += 64) {
    __syncthreads();  // previous iteration done reading Ks/VTs
    {
      const int row_in = lane >> 4, ch = lane & 15;
#pragma unroll
      for (int i = 0; i < 4; ++i) {
        const int row = w * 4 + i * 16 + row_in;
        const int g = ch ^ (row & 15);
        load_lds16(kp + (size_t)(kv0 + row) * 128 + g * 8, &Ks[(w * 4 + i * 16) * 128]);
      }
      const int drow = lane >> 3, ch8 = lane & 7;
#pragma unroll
      for (int i = 0; i < 4; ++i) {
        const int dd = w * 8 + i * 32 + drow;
        const int g = ch8 ^ (dd & 7);
        load_lds16(vp + (size_t)dd * 2048 + kv0 + g * 8, &VTs[(w * 8 + i * 32) * 64]);
      }
    }
    __syncthreads();  // staging complete

    // ---- S^T = K * Q^T : wave computes 64 keys x 16 queries
    f32x4 sacc[4];
#pragma unroll
    for (int im = 0; im < 4; ++im)
#pragma unroll
      for (int r = 0; r < 4; ++r) sacc[im][r] = 0.0f;

#pragma unroll
    for (int ks = 0; ks < 4; ++ks) {
#pragma unroll
      for (int im = 0; im < 4; ++im) {
        const int key = im * 16 + c;
        const int ch = (ks * 4 + quad) ^ c;  // key & 15 == c
        const bf16x8 af = *(const bf16x8*)&Ks[key * 128 + ch * 8];
        sacc[im] = __builtin_amdgcn_mfma_f32_16x16x32_bf16(af, qf[ks], sacc[im], 0, 0, 0);
      }
    }

    // ---- softcap(tanh poly) + exp (fixed max 0); mask only boundary tiles;
    //      write P (C-layout) to wave-private LDS, XOR-swizzled
    const bool need_mask = (kv0 == q0) || (q0 - kv0 >= 961);
#pragma unroll
    for (int im = 0; im < 4; ++im) {
      float pv[4];
#pragma unroll
      for (int r = 0; r < 4; ++r) {
        const float s = sacc[im][r];
        const float u = s * s;
        // 50*tanh(s/50) = s*(1 - u/7500 + 2u^2/9.375e7), |s|<=11.4
        const float cap = s * (1.0f + u * (-1.3333333e-4f + u * 2.1333333e-8f));
        pv[r] = __expf(cap);
      }
      if (need_mask) {
        const int j_base = kv0 + im * 16 + quad * 4;
#pragma unroll
        for (int r = 0; r < 4; ++r) {
          const int j_glob = j_base + r;
          if (!((j_glob <= i_glob) && (i_glob - j_glob < 1024))) pv[r] = 0.0f;
        }
      }
      lsum += (pv[0] + pv[1]) + (pv[2] + pv[3]);
      // keys im*16+quad*4+{0..3} of query c -> chunk l=im*2+(quad>>1), half=quad&1,
      // stored at slot l^(c&7)
      uint2 pk;
      pk.x = pack_trunc(pv[0], pv[1]);
      pk.y = pack_trunc(pv[2], pv[3]);
      *(uint2*)&Psw[c * 64 + ((im * 2 + (quad >> 1)) ^ (c & 7)) * 8 + (quad & 1) * 4] = pk;
    }

    // ---- PV: A-frag = Psw[c][ks*32+quad*8..+7] (chunk ks*4+quad, slot ^(c&7))
#pragma unroll
    for (int ks = 0; ks < 2; ++ks) {
      const bf16x8 pf = *(const bf16x8*)&Psw[c * 64 + ((ks * 4 + quad) ^ (c & 7)) * 8];
#pragma unroll
      for (int jn = 0; jn < 8; ++jn) {
        const int dd = jn * 16 + c;
        const int ch = (ks * 4 + quad) ^ (c & 7);  // dd & 7 == c & 7
        const bf16x8 vf = *(const bf16x8*)&VTs[dd * 64 + ch * 8];
        oacc[jn] = __builtin_amdgcn_mfma_f32_16x16x32_bf16(pf, vf, oacc[jn], 0, 0, 0);
      }
    }
  }

  // ---- normalize + store (cross-quad shuffle reduce; no LDS)
  float lt = lsum;
  lt += __shfl_xor(lt, 16);
  lt += __shfl_xor(lt, 32);       // all lanes: total for query c
  float rl[4];
#pragma unroll
  for (int r = 0; r < 4; ++r)
    rl[r] = __builtin_amdgcn_rcpf(__shfl(lt, quad * 4 + r));

  const size_t obase = ((size_t)(b * 2048 + q0 + w * 16)) * 4096 + hq * 128;
#pragma unroll
  for (int jn = 0; jn < 8; ++jn) {
#pragma unroll
    for (int r = 0; r < 4; ++r) {
      const int q_in = quad * 4 + r;
      attn[obase + (size_t)q_in * 4096 + jn * 16 + c] = f2bf(oacc[jn][r] * rl[r]);
    }
  }
}

// ---------------------------------------------------------------- launch
extern "C" void kernel_launch(void* const* d_in, const int* in_sizes, int n_in,
                              void* d_out, int out_size, void* d_ws, size_t ws_size,
                              hipStream_t stream) {
  (void)in_sizes; (void)n_in; (void)out_size; (void)ws_size;
  const float* x  = (const float*)d_in[0];
  const float* Wq = (const float*)d_in[1];
  const float* Wk = (const float*)d_in[2];
  const float* Wv = (const float*)d_in[3];
  const float* Wo = (const float*)d_in[4];
  float* out = (float*)d_out;
  char* ws = (char*)d_ws;

  u16* xb    = (u16*)(ws + 0);
  u16* vtb   = (u16*)(ws + 0);
  u16* WqkvT = (u16*)(ws + 33554432ULL);
  u16* qb    = (u16*)(ws + 33554432ULL);
  u16* kb    = (u16*)(ws + 67108864ULL);
  u16* vb    = (u16*)(ws + 75497472ULL);
  u16* WoT   = (u16*)(ws + 83886080ULL);
  u16* qkvr  = (u16*)(ws + 117440512ULL);
  u16* attnb = (u16*)(ws + 117440512ULL);

  cast_f32_bf16<<<8192, 256, 0, stream>>>(x, xb);
  transpose_cast_f32_bf16<<<dim3(128, 128), 256, 0, stream>>>(Wq, WqkvT, 4096, 4096);
  transpose_cast_f32_bf16<<<dim3(32, 128), 256, 0, stream>>>(Wk, WqkvT + (size_t)4096 * 4096, 4096, 1024);
  transpose_cast_f32_bf16<<<dim3(32, 128), 256, 0, stream>>>(Wv, WqkvT + (size_t)5120 * 4096, 4096, 1024);
  transpose_cast_f32_bf16<<<dim3(128, 128), 256, 0, stream>>>(Wo, WoT, 4096, 4096);

  gemm_bt<1><<<dim3(48, 32), 256, 0, stream>>>(xb, WqkvT, (void*)qkvr, 4096, 6144, 4096);
  qkv_post<<<49152, 256, 0, stream>>>(qkvr, qb, kb, vb);
  transpose_v<<<dim3(64, 4, 16), 256, 0, stream>>>(vb, vtb);
  attn_fwd<<<dim3(32, 64), 256, 0, stream>>>(qb, kb, vtb, attnb);
  gemm_bt<0><<<dim3(32, 32), 256, 0, stream>>>(attnb, WoT, (void*)out, 4096, 4096, 4096);
}